// Round 8
// baseline (539.324 us; speedup 1.0000x reference)
//
#include <hip/hip_runtime.h>
#include <hip/hip_fp16.h>

#define CCH 64      // channels
#define RPB 32      // rows per bucket
#define PCH 8192    // edges per streaming block
#define GR 64       // rows per gemm block

typedef int int4a __attribute__((ext_vector_type(4), aligned(4)));

// ---- pass 1: per-row in-degree via global atomics (R7 proved scattered
//      4B global traffic is cheap; 3M adds over 150k counters = no hot line) ----
__global__ void __launch_bounds__(256) k_cnt(const int* __restrict__ e0,
        const int* __restrict__ e1, const int* __restrict__ e2,
        int* __restrict__ rcnt, int E, int N) {
    int c = blockIdx.y;
    const int* dd = ((c == 0) ? e0 : (c == 1) ? e1 : e2) + E;
    int* rc = rcnt + (size_t)c * N;
    int base = blockIdx.x * PCH;
    int nE = E - base; if (nE > PCH) nE = PCH;
    int t = threadIdx.x;
    for (int k = t * 4; k < nE; k += 1024) {
        if (k + 3 < nE) {
            int4a d = *(const int4a*)(dd + base + k);
            atomicAdd(&rc[d.x], 1); atomicAdd(&rc[d.y], 1);
            atomicAdd(&rc[d.z], 1); atomicAdd(&rc[d.w], 1);
        } else {
            for (int j = k; j < nE; ++j) atomicAdd(&rc[dd[base + j]], 1);
        }
    }
}

// ---- pass 2: bucket sums (32-row windows of rcnt, L2-hot) -> exclusive
//      scan -> bstart. Also zeroes zrow. ----
__global__ void __launch_bounds__(1024) k_bscan(const int* __restrict__ rcnt,
        int* __restrict__ bstart, __half* __restrict__ zrow,
        int NB, int N, int E) {
    int c = blockIdx.x, t = threadIdx.x;
    if (c == 0 && t < 32) ((float*)zrow)[t] = 0.f;
    __shared__ int sm[1024];
    const int* rc = rcnt + (size_t)c * N;
    int i0 = 2 * t, i1 = 2 * t + 1;
    int v0 = 0, v1 = 0;
    if (i0 < NB) {
        int r0 = i0 * RPB, hi = r0 + RPB; if (hi > N) hi = N;
        for (int r = r0; r < hi; ++r) v0 += rc[r];
    }
    if (i1 < NB) {
        int r0 = i1 * RPB, hi = r0 + RPB; if (hi > N) hi = N;
        for (int r = r0; r < hi; ++r) v1 += rc[r];
    }
    sm[t] = v0 + v1;
    __syncthreads();
    #pragma unroll
    for (int off = 1; off < 1024; off <<= 1) {
        int u = (t >= off) ? sm[t - off] : 0;
        __syncthreads();
        sm[t] += u;
        __syncthreads();
    }
    int ex = sm[t] - (v0 + v1);
    if (i0 < NB) bstart[c * (NB + 1) + i0] = ex;
    if (i1 < NB) bstart[c * (NB + 1) + i1] = ex + v0;
    if (t == 0) bstart[c * (NB + 1) + NB] = E;
}

// ---- pass 3: row starts rs = bstart[bucket] + intra-bucket prefix(rcnt);
//      init scatter cursors; dinv = rsqrt(deg+1). ----
__global__ void __launch_bounds__(256) k_rs(const int* __restrict__ rcnt,
        const int* __restrict__ bstart, int* __restrict__ rs,
        int* __restrict__ cursor, float* __restrict__ dinv,
        int N, int NB, int E) {
    int c = blockIdx.y;
    int row = blockIdx.x * 256 + threadIdx.x;
    int l = threadIdx.x & 31;
    int v = (row < N) ? rcnt[(size_t)c * N + row] : 0;
    int s = v;
    #pragma unroll
    for (int off = 1; off < RPB; off <<= 1) {
        int u = __shfl_up(s, off, RPB);
        if (l >= off) s += u;
    }
    if (row < N) {
        int ex = bstart[c * (NB + 1) + (row >> 5)] + s - v;
        rs[c * (N + 1) + row] = ex;
        cursor[(size_t)c * N + row] = ex;
        dinv[(size_t)c * N + row] = rsqrtf((float)(v + 1));
    }
    if (blockIdx.x == 0 && threadIdx.x == 0) rs[c * (N + 1) + N] = E;
}

// ---- pass 4: single-pass scatter. Row order within a list is arbitrary
//      (sum is order-independent within fp16 tolerance). Replaces the whole
//      H/colscan/part2/sort32 partition pipeline. ----
__global__ void __launch_bounds__(256) k_scat(const int* __restrict__ e0,
        const int* __restrict__ e1, const int* __restrict__ e2,
        int* __restrict__ cursor, int* __restrict__ sdat, int E, int N) {
    int c = blockIdx.y;
    const int* ed = (c == 0) ? e0 : (c == 1) ? e1 : e2;
    int* cur = cursor + (size_t)c * N;
    int* so = sdat + (size_t)c * E;
    int base = blockIdx.x * PCH;
    int nE = E - base; if (nE > PCH) nE = PCH;
    int t = threadIdx.x;
    for (int k = t * 4; k < nE; k += 1024) {
        if (k + 3 < nE) {
            int4a s4 = *(const int4a*)(ed + base + k);
            int4a d4 = *(const int4a*)(ed + E + base + k);
            int sl;
            sl = atomicAdd(&cur[d4.x], 1); so[sl] = s4.x;
            sl = atomicAdd(&cur[d4.y], 1); so[sl] = s4.y;
            sl = atomicAdd(&cur[d4.z], 1); so[sl] = s4.z;
            sl = atomicAdd(&cur[d4.w], 1); so[sl] = s4.w;
        } else {
            for (int j = k; j < nE; ++j) {
                int sl = atomicAdd(&cur[ed[E + base + j]], 1);
                so[sl] = ed[base + j];
            }
        }
    }
}

// ---- h16[c,row,:] = fp16( (x_row . W_c) * dinv[c,row] ), register-tiled.
//      Star path computes BOTH conv0 and conv1 from ONE x_star read. ----
__global__ void __launch_bounds__(256) k_gemm_all(const float* __restrict__ xs_,
        const float* __restrict__ xg_, const float* __restrict__ W0,
        const float* __restrict__ W1, const float* __restrict__ W2,
        const float* __restrict__ dinv, __half* __restrict__ h16, int N) {
    int star = (blockIdx.y == 0);
    const float* x = star ? xs_ : xg_;
    __shared__ float Ws[2][CCH * CCH];    // 32 KB (gal uses [0] only)
    __shared__ float xT[CCH * (GR + 1)];  // [k][row], stride 65
    int t = threadIdx.x;
    int row0 = blockIdx.x * GR;
    size_t NC = (size_t)N * CCH;
    if (star) {
        #pragma unroll
        for (int j = 0; j < 4; ++j) {
            int idx = j * 1024 + t * 4;
            *(float4*)(&Ws[0][idx]) = *(const float4*)(W0 + idx);
            *(float4*)(&Ws[1][idx]) = *(const float4*)(W1 + idx);
        }
    } else {
        #pragma unroll
        for (int j = 0; j < 4; ++j) {
            int idx = j * 1024 + t * 4;
            *(float4*)(&Ws[0][idx]) = *(const float4*)(W2 + idx);
        }
    }
    #pragma unroll
    for (int j = 0; j < 4; ++j) {
        int idx = t + j * 256;
        int r = idx >> 4;
        int c0 = (idx & 15) * 4;
        int row = row0 + r;
        float4 v = make_float4(0.f, 0.f, 0.f, 0.f);
        if (row < N) v = *(const float4*)(x + (size_t)row * CCH + c0);
        xT[(c0 + 0) * (GR + 1) + r] = v.x;
        xT[(c0 + 1) * (GR + 1) + r] = v.y;
        xT[(c0 + 2) * (GR + 1) + r] = v.z;
        xT[(c0 + 3) * (GR + 1) + r] = v.w;
    }
    __syncthreads();
    int c4 = (t & 15) * 4;
    int r0 = (t >> 4) * 4;
    if (star) {
        float4 a0 = make_float4(0.f, 0.f, 0.f, 0.f), a1 = a0, a2 = a0, a3 = a0;
        float4 d0 = a0, d1 = a0, d2 = a0, d3 = a0;
        #pragma unroll 4
        for (int k = 0; k < CCH; ++k) {
            float4 wv = *(float4*)(&Ws[0][k * CCH + c4]);
            float4 uv = *(float4*)(&Ws[1][k * CCH + c4]);
            float x0 = xT[k * (GR + 1) + r0 + 0];
            float x1 = xT[k * (GR + 1) + r0 + 1];
            float x2 = xT[k * (GR + 1) + r0 + 2];
            float x3 = xT[k * (GR + 1) + r0 + 3];
            a0.x += x0 * wv.x; a0.y += x0 * wv.y; a0.z += x0 * wv.z; a0.w += x0 * wv.w;
            a1.x += x1 * wv.x; a1.y += x1 * wv.y; a1.z += x1 * wv.z; a1.w += x1 * wv.w;
            a2.x += x2 * wv.x; a2.y += x2 * wv.y; a2.z += x2 * wv.z; a2.w += x2 * wv.w;
            a3.x += x3 * wv.x; a3.y += x3 * wv.y; a3.z += x3 * wv.z; a3.w += x3 * wv.w;
            d0.x += x0 * uv.x; d0.y += x0 * uv.y; d0.z += x0 * uv.z; d0.w += x0 * uv.w;
            d1.x += x1 * uv.x; d1.y += x1 * uv.y; d1.z += x1 * uv.z; d1.w += x1 * uv.w;
            d2.x += x2 * uv.x; d2.y += x2 * uv.y; d2.z += x2 * uv.z; d2.w += x2 * uv.w;
            d3.x += x3 * uv.x; d3.y += x3 * uv.y; d3.z += x3 * uv.z; d3.w += x3 * uv.w;
        }
        float4 av[4] = {a0, a1, a2, a3};
        float4 dv4[4] = {d0, d1, d2, d3};
        #pragma unroll
        for (int i = 0; i < 4; ++i) {
            int row = row0 + r0 + i;
            if (row < N) {
                float dd0 = dinv[row];
                float dd1 = dinv[N + row];
                union { __half2 h2[2]; float2 f2; } u;
                u.h2[0] = __floats2half2_rn(av[i].x * dd0, av[i].y * dd0);
                u.h2[1] = __floats2half2_rn(av[i].z * dd0, av[i].w * dd0);
                *(float2*)(h16 + (size_t)row * CCH + c4) = u.f2;
                u.h2[0] = __floats2half2_rn(dv4[i].x * dd1, dv4[i].y * dd1);
                u.h2[1] = __floats2half2_rn(dv4[i].z * dd1, dv4[i].w * dd1);
                *(float2*)(h16 + NC + (size_t)row * CCH + c4) = u.f2;
            }
        }
    } else {
        float4 a0 = make_float4(0.f, 0.f, 0.f, 0.f), a1 = a0, a2 = a0, a3 = a0;
        #pragma unroll 8
        for (int k = 0; k < CCH; ++k) {
            float4 wv = *(float4*)(&Ws[0][k * CCH + c4]);
            float x0 = xT[k * (GR + 1) + r0 + 0];
            float x1 = xT[k * (GR + 1) + r0 + 1];
            float x2 = xT[k * (GR + 1) + r0 + 2];
            float x3 = xT[k * (GR + 1) + r0 + 3];
            a0.x += x0 * wv.x; a0.y += x0 * wv.y; a0.z += x0 * wv.z; a0.w += x0 * wv.w;
            a1.x += x1 * wv.x; a1.y += x1 * wv.y; a1.z += x1 * wv.z; a1.w += x1 * wv.w;
            a2.x += x2 * wv.x; a2.y += x2 * wv.y; a2.z += x2 * wv.z; a2.w += x2 * wv.w;
            a3.x += x3 * wv.x; a3.y += x3 * wv.y; a3.z += x3 * wv.z; a3.w += x3 * wv.w;
        }
        float4 av[4] = {a0, a1, a2, a3};
        #pragma unroll
        for (int i = 0; i < 4; ++i) {
            int row = row0 + r0 + i;
            if (row < N) {
                float dd = dinv[2 * N + row];
                union { __half2 h2[2]; float2 f2; } u;
                u.h2[0] = __floats2half2_rn(av[i].x * dd, av[i].y * dd);
                u.h2[1] = __floats2half2_rn(av[i].z * dd, av[i].w * dd);
                *(float2*)(h16 + 2 * NC + (size_t)row * CCH + c4) = u.f2;
            }
        }
    }
}

// ---- gather 4 fp16 channels (8B dwordx2) from a row pointer ----
__device__ __forceinline__ float4 gat4p(const __half* __restrict__ p, int l16) {
    union { float2 f2; __half2 h2[2]; } u;
    u.f2 = ((const float2*)p)[l16];
    float2 a = __half22float2(u.h2[0]);
    float2 b = __half22float2(u.h2[1]);
    return make_float4(a.x, a.y, b.x, b.y);
}

__device__ __forceinline__ void acc4(float4& a, float4 v) {
    a.x += v.x; a.y += v.y; a.z += v.z; a.w += v.w;
}

// ---- fused pull: wave per row; four quarter-waves (16 lanes x 4ch) walk
//      4 list segments. Unpredicated 8-wide steady state + ONE masked
//      8-wide tail via L1-hot zero row (measured 65-67 us, R5). ----
__global__ void __launch_bounds__(256) k_pull(const int* __restrict__ rs,
        const int* __restrict__ sdat, const __half* __restrict__ h16,
        const float* __restrict__ dinv, const __half* __restrict__ zrow,
        const float* __restrict__ b0, const float* __restrict__ b1,
        const float* __restrict__ b2,
        float* __restrict__ out, int N, int E) {
    int row = blockIdx.x * 4 + (threadIdx.x >> 6);
    if (row >= 2 * N) return;
    int lane = threadIdx.x & 63;
    int q = lane >> 4;          // quarter 0..3
    int l16 = lane & 15;
    size_t NC = (size_t)N * CCH;

    const __half* hcL;
    const int* sdL;
    int beg, end;
    float ddL;
    float4 bias;
    float* op;
    float4 acc = make_float4(0.f, 0.f, 0.f, 0.f);
    if (row < N) {                          // star: q0,q1=conv0; q2,q3=conv1
        int cv = q >> 1;
        const int* rsA = rs + cv * (N + 1);
        int bg = rsA[row], eg = rsA[row + 1];
        int mid = (bg + eg) >> 1;
        beg = (q & 1) ? mid : bg;
        end = (q & 1) ? eg : mid;
        hcL = h16 + (size_t)cv * NC;
        sdL = sdat + (size_t)cv * E;
        ddL = dinv[cv * N + row];
        if (!(q & 1)) acc = gat4p(hcL + (size_t)row * CCH, l16); // self-loop
        float4 bv0 = ((const float4*)b0)[l16];
        float4 bv1 = ((const float4*)b1)[l16];
        bias = make_float4(bv0.x + bv1.x, bv0.y + bv1.y,
                           bv0.z + bv1.z, bv0.w + bv1.w);
        op = out + (size_t)row * CCH;
    } else {                                // gal: 4 segments of one list
        int r = row - N;
        const int* rs2 = rs + 2 * (N + 1);
        int bg = rs2[r], eg = rs2[r + 1];
        int len = eg - bg;
        beg = bg + ((len * q) >> 2);
        end = bg + ((len * (q + 1)) >> 2);
        hcL = h16 + 2 * NC;
        sdL = sdat + 2 * (size_t)E;
        ddL = dinv[2 * N + r];
        if (q == 0) acc = gat4p(hcL + (size_t)r * CCH, l16);
        bias = ((const float4*)b2)[l16];
        op = out + NC + (size_t)r * CCH;
    }

    int i = beg;
    for (; i + 7 < end; i += 8) {           // unpredicated steady state
        int4a q0 = *(const int4a*)(sdL + i);
        int4a q1 = *(const int4a*)(sdL + i + 4);
        float4 v0 = gat4p(hcL + (size_t)q0.x * CCH, l16);
        float4 v1 = gat4p(hcL + (size_t)q0.y * CCH, l16);
        float4 v2 = gat4p(hcL + (size_t)q0.z * CCH, l16);
        float4 v3 = gat4p(hcL + (size_t)q0.w * CCH, l16);
        float4 v4 = gat4p(hcL + (size_t)q1.x * CCH, l16);
        float4 v5 = gat4p(hcL + (size_t)q1.y * CCH, l16);
        float4 v6 = gat4p(hcL + (size_t)q1.z * CCH, l16);
        float4 v7 = gat4p(hcL + (size_t)q1.w * CCH, l16);
        acc4(acc, v0); acc4(acc, v1); acc4(acc, v2); acc4(acc, v3);
        acc4(acc, v4); acc4(acc, v5); acc4(acc, v6); acc4(acc, v7);
    }
    if (i < end) {                          // ONE masked 8-wide tail shot
        // index over-read stays inside workspace (sdat is followed by rcnt).
        int4a q0 = *(const int4a*)(sdL + i);
        int4a q1 = *(const int4a*)(sdL + i + 4);
        const __half* p0 = hcL + (size_t)q0.x * CCH;   // i < end: valid
        const __half* p1 = (i + 1 < end) ? hcL + (size_t)q0.y * CCH : zrow;
        const __half* p2 = (i + 2 < end) ? hcL + (size_t)q0.z * CCH : zrow;
        const __half* p3 = (i + 3 < end) ? hcL + (size_t)q0.w * CCH : zrow;
        const __half* p4 = (i + 4 < end) ? hcL + (size_t)q1.x * CCH : zrow;
        const __half* p5 = (i + 5 < end) ? hcL + (size_t)q1.y * CCH : zrow;
        const __half* p6 = (i + 6 < end) ? hcL + (size_t)q1.z * CCH : zrow;
        const __half* p7 = (i + 7 < end) ? hcL + (size_t)q1.w * CCH : zrow;
        float4 v0 = gat4p(p0, l16);
        float4 v1 = gat4p(p1, l16);
        float4 v2 = gat4p(p2, l16);
        float4 v3 = gat4p(p3, l16);
        float4 v4 = gat4p(p4, l16);
        float4 v5 = gat4p(p5, l16);
        float4 v6 = gat4p(p6, l16);
        float4 v7 = gat4p(p7, l16);
        acc4(acc, v0); acc4(acc, v1); acc4(acc, v2); acc4(acc, v3);
        acc4(acc, v4); acc4(acc, v5); acc4(acc, v6); acc4(acc, v7);
    }

    float4 t;
    t.x = acc.x * ddL; t.y = acc.y * ddL; t.z = acc.z * ddL; t.w = acc.w * ddL;
    t.x += __shfl_xor(t.x, 16, 64); t.y += __shfl_xor(t.y, 16, 64);
    t.z += __shfl_xor(t.z, 16, 64); t.w += __shfl_xor(t.w, 16, 64);
    t.x += __shfl_xor(t.x, 32, 64); t.y += __shfl_xor(t.y, 32, 64);
    t.z += __shfl_xor(t.z, 32, 64); t.w += __shfl_xor(t.w, 32, 64);
    if (lane < 16) {
        t.x += bias.x; t.y += bias.y; t.z += bias.z; t.w += bias.w;
        ((float4*)op)[l16] = t;
    }
}

static inline size_t align256(size_t x) { return (x + 255) & ~(size_t)255; }

extern "C" void kernel_launch(void* const* d_in, const int* in_sizes, int n_in,
                              void* d_out, int out_size, void* d_ws, size_t ws_size,
                              hipStream_t stream) {
    const float* x_star = (const float*)d_in[0];
    const float* x_gal  = (const float*)d_in[1];
    const int*   e_ssn  = (const int*)d_in[2];
    const int*   e_ssf  = (const int*)d_in[3];
    const int*   e_ggn  = (const int*)d_in[4];
    const float* W_ssn  = (const float*)d_in[5];
    const float* W_ssf  = (const float*)d_in[6];
    const float* W_ggn  = (const float*)d_in[7];
    const float* b_ssn  = (const float*)d_in[8];
    const float* b_ssf  = (const float*)d_in[9];
    const float* b_ggn  = (const float*)d_in[10];

    const int N  = in_sizes[0] / CCH;       // 50000
    const int E  = in_sizes[2] / 2;         // 1000000
    const size_t NC = (size_t)N * CCH;
    const int NB   = (N + RPB - 1) / RPB;   // 1563 buckets per conv
    const int NBLK = (E + PCH - 1) / PCH;   // 123 streaming blocks per conv

    // workspace layout
    char* w = (char*)d_ws;
    __half*   h16    = (__half*)w;   w += align256((size_t)3 * NC * 2);
    float*    dinv   = (float*)w;    w += align256((size_t)3 * N * 4);
    int*      sdat   = (int*)w;      w += align256((size_t)3 * E * 4);
    int*      rcnt   = (int*)w;      w += align256((size_t)3 * N * 4);
    int*      cursor = (int*)w;      w += align256((size_t)3 * N * 4);
    int*      bstart = (int*)w;      w += align256((size_t)3 * (NB + 1) * 4);
    int*      rs     = (int*)w;      w += align256((size_t)3 * (N + 1) * 4);
    __half*   zrow   = (__half*)w;   w += align256((size_t)CCH * 2);

    const int B = 256;

    hipMemsetAsync(rcnt, 0, (size_t)3 * N * 4, stream);
    k_cnt<<<dim3(NBLK, 3), B, 0, stream>>>(e_ssn, e_ssf, e_ggn, rcnt, E, N);
    k_bscan<<<3, 1024, 0, stream>>>(rcnt, bstart, zrow, NB, N, E);
    k_rs<<<dim3((N + 255) / 256, 3), B, 0, stream>>>(rcnt, bstart, rs, cursor,
                                                     dinv, N, NB, E);
    k_scat<<<dim3(NBLK, 3), B, 0, stream>>>(e_ssn, e_ssf, e_ggn, cursor, sdat, E, N);
    k_gemm_all<<<dim3((N + GR - 1) / GR, 2), B, 0, stream>>>(x_star, x_gal,
                                                             W_ssn, W_ssf, W_ggn,
                                                             dinv, h16, N);
    k_pull<<<(2 * N + 3) / 4, B, 0, stream>>>(rs, sdat, h16, dinv, zrow,
                                              b_ssn, b_ssf, b_ggn,
                                              (float*)d_out, N, E);
}

// Round 9
// 234.045 us; speedup vs baseline: 2.3044x; 2.3044x over previous
//
#include <hip/hip_runtime.h>
#include <hip/hip_fp16.h>

#define CCH 64      // channels
#define BKT 256     // rows per bucket (was 32: 8x fewer buckets -> 8x longer
                    // copy-out runs, 8x smaller per-block loops)
#define PCH 8192    // edges per partition block
#define NBMAX 200   // >= NB = ceil(50000/256) = 196
#define GR 64       // rows per gemm block
#define STCAP 8192  // sort32 LDS staging capacity (recs); bucket mean 5102, +43 sigma

typedef int int4a __attribute__((ext_vector_type(4), aligned(4)));

// ---- pass A: per-block bucket histogram -> H[c][blk][b]; cnt totals via
//      global atomics (R5 scheme, measured-cheap at this scale). ----
__global__ void __launch_bounds__(256) k_hist(const int* __restrict__ e0,
        const int* __restrict__ e1, const int* __restrict__ e2,
        int* __restrict__ H, int* __restrict__ cnt, int E, int NB, int NBLK) {
    int c = blockIdx.y;
    const int* dd = ((c == 0) ? e0 : (c == 1) ? e1 : e2) + E;
    int base = blockIdx.x * PCH;
    int nE = E - base; if (nE > PCH) nE = PCH;
    __shared__ int hist[NBMAX];
    int t = threadIdx.x;
    if (t < NB) hist[t] = 0;
    __syncthreads();
    for (int k = t * 4; k < nE; k += 1024) {
        if (k + 3 < nE) {
            int4a d = *(const int4a*)(dd + base + k);
            atomicAdd(&hist[d.x >> 8], 1); atomicAdd(&hist[d.y >> 8], 1);
            atomicAdd(&hist[d.z >> 8], 1); atomicAdd(&hist[d.w >> 8], 1);
        } else {
            for (int j = k; j < nE; ++j) atomicAdd(&hist[dd[base + j] >> 8], 1);
        }
    }
    __syncthreads();
    int* Hrow = H + ((size_t)c * NBLK + blockIdx.x) * NB;
    if (t < NB) {
        int h = hist[t];
        Hrow[t] = h;
        if (h) atomicAdd(&cnt[c * NB + t], h);
    }
}

// ---- exclusive scan of NB bucket totals per conv -> bstart; zeroes zrow ----
__global__ void __launch_bounds__(1024) k_bscan(const int* __restrict__ cnt,
        int* __restrict__ bstart, __half* __restrict__ zrow, int NB, int E) {
    int c = blockIdx.x, t = threadIdx.x;
    if (c == 0 && t < 32) ((float*)zrow)[t] = 0.f;
    __shared__ int sm[1024];
    int i0 = 2 * t, i1 = 2 * t + 1;
    int v0 = (i0 < NB) ? cnt[c * NB + i0] : 0;
    int v1 = (i1 < NB) ? cnt[c * NB + i1] : 0;
    sm[t] = v0 + v1;
    __syncthreads();
    #pragma unroll
    for (int off = 1; off < 1024; off <<= 1) {
        int u = (t >= off) ? sm[t - off] : 0;
        __syncthreads();
        sm[t] += u;
        __syncthreads();
    }
    int ex = sm[t] - (v0 + v1);
    if (i0 < NB) bstart[c * (NB + 1) + i0] = ex;
    if (i1 < NB) bstart[c * (NB + 1) + i1] = ex + v0;
    if (t == 0) bstart[c * (NB + 1) + NB] = E;
}

// ---- pass B: per-bucket scan over blocks: H <- bstart + prefix ----
__global__ void __launch_bounds__(256) k_colscan(int* __restrict__ H,
        const int* __restrict__ bstart, int NB, int NBLK) {
    int c = blockIdx.y;
    int b = blockIdx.x * 4 + (threadIdx.x >> 6);
    if (b >= NB) return;
    int l = threadIdx.x & 63;
    int* Hc = H + (size_t)c * NBLK * NB;
    int run = bstart[c * (NB + 1) + b];
    for (int c0 = 0; c0 < NBLK; c0 += 64) {
        int blk = c0 + l;
        int v = (blk < NBLK) ? Hc[(size_t)blk * NB + b] : 0;
        int s = v;
        #pragma unroll
        for (int off = 1; off < 64; off <<= 1) {
            int u = __shfl_up(s, off, 64);
            if (l >= off) s += u;
        }
        if (blk < NBLK) Hc[(size_t)blk * NB + b] = run + s - v;
        run += __shfl(s, 63, 64);
    }
}

// ---- pass C: LDS-STAGED partition (H-diff local counts, verified R1-R7).
//      With BKT=256 the copy-out runs are ~42 recs = 168 B -> ~1.1x write
//      amplification (R8 taught the 64B-line writeback cost). ----
__global__ void __launch_bounds__(256) k_part2(const int* __restrict__ e0,
        const int* __restrict__ e1, const int* __restrict__ e2,
        const int* __restrict__ H, const int* __restrict__ bstart,
        unsigned* __restrict__ bdata, int E, int NB, int NBLK) {
    int c = blockIdx.y;
    const int* ed = (c == 0) ? e0 : (c == 1) ? e1 : e2;
    int base = blockIdx.x * PCH;
    int nE = E - base; if (nE > PCH) nE = PCH;
    __shared__ unsigned staged[PCH];    // 32 KB
    __shared__ int hist[NBMAX];
    __shared__ int off[NBMAX];
    __shared__ int sm[256];
    int t = threadIdx.x;
    const int* Hcur = H + ((size_t)c * NBLK + blockIdx.x) * NB;
    const int* Hnxt = (blockIdx.x == NBLK - 1) ? (bstart + c * (NB + 1) + 1)
                                               : (Hcur + NB);
    if (t < NB) {
        int cu = Hcur[t];
        off[t] = cu;                    // absolute global offset (post-colscan)
        hist[t] = Hnxt[t] - cu;         // this block's local count for bucket t
    }
    __syncthreads();
    int s = (t < NB) ? hist[t] : 0;
    sm[t] = s;
    __syncthreads();
    #pragma unroll
    for (int o = 1; o < 256; o <<= 1) {
        int u = (t >= o) ? sm[t - o] : 0;
        __syncthreads();
        sm[t] += u;
        __syncthreads();
    }
    if (t < NB) {
        int run = sm[t] - s;            // exclusive prefix
        off[t] -= run;                  // global offset minus staging start
        hist[t] = run;                  // staging cursor
    }
    __syncthreads();
    for (int k = t * 4; k < nE; k += 1024) {
        if (k + 3 < nE) {
            int4a s4 = *(const int4a*)(ed + base + k);
            int4a d4 = *(const int4a*)(ed + E + base + k);
            int sl;
            sl = atomicAdd(&hist[d4.x >> 8], 1); staged[sl] = (unsigned)s4.x | ((unsigned)d4.x << 16);
            sl = atomicAdd(&hist[d4.y >> 8], 1); staged[sl] = (unsigned)s4.y | ((unsigned)d4.y << 16);
            sl = atomicAdd(&hist[d4.z >> 8], 1); staged[sl] = (unsigned)s4.z | ((unsigned)d4.z << 16);
            sl = atomicAdd(&hist[d4.w >> 8], 1); staged[sl] = (unsigned)s4.w | ((unsigned)d4.w << 16);
        } else {
            for (int j = k; j < nE; ++j) {
                int s0 = ed[base + j];
                int d0 = ed[E + base + j];
                int sl = atomicAdd(&hist[d0 >> 8], 1);
                staged[sl] = (unsigned)s0 | ((unsigned)d0 << 16);
            }
        }
    }
    __syncthreads();
    unsigned* bo = bdata + (size_t)c * E;
    for (int sI = t; sI < nE; sI += 256) {
        unsigned rec = staged[sI];
        int b = (int)(rec >> 16) >> 8;
        bo[off[b] + sI] = rec;
    }
}

// ---- within-bucket 256-way counting sort: ONE bucket (256 rows) per block.
//      Region ~5102 recs staged in LDS; scatter stays in a ~20 KB block-local
//      window (the pattern R0-R7 measured cheap). Emits rs + dinv. ----
__global__ void __launch_bounds__(256) k_sort32(const unsigned* __restrict__ bdata,
        const int* __restrict__ bstart, int* __restrict__ sdat,
        int* __restrict__ rs, float* __restrict__ dinv, int E, int N, int NB) {
    int c = blockIdx.y;
    int b = blockIdx.x;
    __shared__ unsigned staged[STCAP];  // 32 KB
    __shared__ int cnt[BKT];
    __shared__ int cur[BKT];
    __shared__ int wsum[4];
    int t = threadIdx.x;
    cnt[t] = 0;
    __syncthreads();
    int s0 = bstart[c * (NB + 1) + b];
    int sE = bstart[c * (NB + 1) + b + 1];
    int n = sE - s0;
    const unsigned* bd = bdata + (size_t)c * E;
    bool fits = (n <= STCAP);
    if (fits) {
        for (int i = t; i < n; i += 256) staged[i] = bd[s0 + i];
        __syncthreads();
        for (int i = t; i < n; i += 256)
            atomicAdd(&cnt[(staged[i] >> 16) & 255], 1);
    } else {
        for (int i = s0 + t; i < sE; i += 256)
            atomicAdd(&cnt[(bd[i] >> 16) & 255], 1);
    }
    __syncthreads();
    // 256-wide exclusive scan of cnt: wave64 shfl scan + wave-sum combine
    int v = cnt[t];
    int s = v;
    #pragma unroll
    for (int off = 1; off < 64; off <<= 1) {
        int u = __shfl_up(s, off, 64);
        if ((t & 63) >= off) s += u;
    }
    int w = t >> 6;
    if ((t & 63) == 63) wsum[w] = s;
    __syncthreads();
    int wpre = 0;
    #pragma unroll
    for (int j = 0; j < 4; ++j) if (j < w) wpre += wsum[j];
    int ex = s0 + wpre + s - v;         // exclusive prefix -> row start
    cur[t] = ex;
    int row = b * BKT + t;
    if (row < N) {
        rs[c * (N + 1) + row] = ex;
        dinv[c * N + row] = rsqrtf((float)(v + 1));
    }
    if (b == 0 && t == 0) rs[c * (N + 1) + N] = E;
    __syncthreads();
    int* so = sdat + (size_t)c * E;
    if (fits) {
        for (int i = t; i < n; i += 256) {
            unsigned r = staged[i];
            int slot = atomicAdd(&cur[(r >> 16) & 255], 1);
            so[slot] = (int)(r & 0xFFFFu);
        }
    } else {
        for (int i = s0 + t; i < sE; i += 256) {
            unsigned r = bd[i];
            int slot = atomicAdd(&cur[(r >> 16) & 255], 1);
            so[slot] = (int)(r & 0xFFFFu);
        }
    }
}

// ---- h16[c,row,:] = fp16( (x_row . W_c) * dinv[c,row] ), register-tiled.
//      Star path computes BOTH conv0 and conv1 from ONE x_star read. ----
__global__ void __launch_bounds__(256) k_gemm_all(const float* __restrict__ xs_,
        const float* __restrict__ xg_, const float* __restrict__ W0,
        const float* __restrict__ W1, const float* __restrict__ W2,
        const float* __restrict__ dinv, __half* __restrict__ h16, int N) {
    int star = (blockIdx.y == 0);
    const float* x = star ? xs_ : xg_;
    __shared__ float Ws[2][CCH * CCH];    // 32 KB (gal uses [0] only)
    __shared__ float xT[CCH * (GR + 1)];  // [k][row], stride 65
    int t = threadIdx.x;
    int row0 = blockIdx.x * GR;
    size_t NC = (size_t)N * CCH;
    if (star) {
        #pragma unroll
        for (int j = 0; j < 4; ++j) {
            int idx = j * 1024 + t * 4;
            *(float4*)(&Ws[0][idx]) = *(const float4*)(W0 + idx);
            *(float4*)(&Ws[1][idx]) = *(const float4*)(W1 + idx);
        }
    } else {
        #pragma unroll
        for (int j = 0; j < 4; ++j) {
            int idx = j * 1024 + t * 4;
            *(float4*)(&Ws[0][idx]) = *(const float4*)(W2 + idx);
        }
    }
    #pragma unroll
    for (int j = 0; j < 4; ++j) {
        int idx = t + j * 256;
        int r = idx >> 4;
        int c0 = (idx & 15) * 4;
        int row = row0 + r;
        float4 v = make_float4(0.f, 0.f, 0.f, 0.f);
        if (row < N) v = *(const float4*)(x + (size_t)row * CCH + c0);
        xT[(c0 + 0) * (GR + 1) + r] = v.x;
        xT[(c0 + 1) * (GR + 1) + r] = v.y;
        xT[(c0 + 2) * (GR + 1) + r] = v.z;
        xT[(c0 + 3) * (GR + 1) + r] = v.w;
    }
    __syncthreads();
    int c4 = (t & 15) * 4;
    int r0 = (t >> 4) * 4;
    if (star) {
        float4 a0 = make_float4(0.f, 0.f, 0.f, 0.f), a1 = a0, a2 = a0, a3 = a0;
        float4 d0 = a0, d1 = a0, d2 = a0, d3 = a0;
        #pragma unroll 4
        for (int k = 0; k < CCH; ++k) {
            float4 wv = *(float4*)(&Ws[0][k * CCH + c4]);
            float4 uv = *(float4*)(&Ws[1][k * CCH + c4]);
            float x0 = xT[k * (GR + 1) + r0 + 0];
            float x1 = xT[k * (GR + 1) + r0 + 1];
            float x2 = xT[k * (GR + 1) + r0 + 2];
            float x3 = xT[k * (GR + 1) + r0 + 3];
            a0.x += x0 * wv.x; a0.y += x0 * wv.y; a0.z += x0 * wv.z; a0.w += x0 * wv.w;
            a1.x += x1 * wv.x; a1.y += x1 * wv.y; a1.z += x1 * wv.z; a1.w += x1 * wv.w;
            a2.x += x2 * wv.x; a2.y += x2 * wv.y; a2.z += x2 * wv.z; a2.w += x2 * wv.w;
            a3.x += x3 * wv.x; a3.y += x3 * wv.y; a3.z += x3 * wv.z; a3.w += x3 * wv.w;
            d0.x += x0 * uv.x; d0.y += x0 * uv.y; d0.z += x0 * uv.z; d0.w += x0 * uv.w;
            d1.x += x1 * uv.x; d1.y += x1 * uv.y; d1.z += x1 * uv.z; d1.w += x1 * uv.w;
            d2.x += x2 * uv.x; d2.y += x2 * uv.y; d2.z += x2 * uv.z; d2.w += x2 * uv.w;
            d3.x += x3 * uv.x; d3.y += x3 * uv.y; d3.z += x3 * uv.z; d3.w += x3 * uv.w;
        }
        float4 av[4] = {a0, a1, a2, a3};
        float4 dv4[4] = {d0, d1, d2, d3};
        #pragma unroll
        for (int i = 0; i < 4; ++i) {
            int row = row0 + r0 + i;
            if (row < N) {
                float dd0 = dinv[row];
                float dd1 = dinv[N + row];
                union { __half2 h2[2]; float2 f2; } u;
                u.h2[0] = __floats2half2_rn(av[i].x * dd0, av[i].y * dd0);
                u.h2[1] = __floats2half2_rn(av[i].z * dd0, av[i].w * dd0);
                *(float2*)(h16 + (size_t)row * CCH + c4) = u.f2;
                u.h2[0] = __floats2half2_rn(dv4[i].x * dd1, dv4[i].y * dd1);
                u.h2[1] = __floats2half2_rn(dv4[i].z * dd1, dv4[i].w * dd1);
                *(float2*)(h16 + NC + (size_t)row * CCH + c4) = u.f2;
            }
        }
    } else {
        float4 a0 = make_float4(0.f, 0.f, 0.f, 0.f), a1 = a0, a2 = a0, a3 = a0;
        #pragma unroll 8
        for (int k = 0; k < CCH; ++k) {
            float4 wv = *(float4*)(&Ws[0][k * CCH + c4]);
            float x0 = xT[k * (GR + 1) + r0 + 0];
            float x1 = xT[k * (GR + 1) + r0 + 1];
            float x2 = xT[k * (GR + 1) + r0 + 2];
            float x3 = xT[k * (GR + 1) + r0 + 3];
            a0.x += x0 * wv.x; a0.y += x0 * wv.y; a0.z += x0 * wv.z; a0.w += x0 * wv.w;
            a1.x += x1 * wv.x; a1.y += x1 * wv.y; a1.z += x1 * wv.z; a1.w += x1 * wv.w;
            a2.x += x2 * wv.x; a2.y += x2 * wv.y; a2.z += x2 * wv.z; a2.w += x2 * wv.w;
            a3.x += x3 * wv.x; a3.y += x3 * wv.y; a3.z += x3 * wv.z; a3.w += x3 * wv.w;
        }
        float4 av[4] = {a0, a1, a2, a3};
        #pragma unroll
        for (int i = 0; i < 4; ++i) {
            int row = row0 + r0 + i;
            if (row < N) {
                float dd = dinv[2 * N + row];
                union { __half2 h2[2]; float2 f2; } u;
                u.h2[0] = __floats2half2_rn(av[i].x * dd, av[i].y * dd);
                u.h2[1] = __floats2half2_rn(av[i].z * dd, av[i].w * dd);
                *(float2*)(h16 + 2 * NC + (size_t)row * CCH + c4) = u.f2;
            }
        }
    }
}

// ---- gather 4 fp16 channels (8B dwordx2) from a row pointer ----
__device__ __forceinline__ float4 gat4p(const __half* __restrict__ p, int l16) {
    union { float2 f2; __half2 h2[2]; } u;
    u.f2 = ((const float2*)p)[l16];
    float2 a = __half22float2(u.h2[0]);
    float2 b = __half22float2(u.h2[1]);
    return make_float4(a.x, a.y, b.x, b.y);
}

__device__ __forceinline__ void acc4(float4& a, float4 v) {
    a.x += v.x; a.y += v.y; a.z += v.z; a.w += v.w;
}

// ---- fused pull (R5-measured 65 us total), split into star/gal launches
//      via row0 so preprocessing kernels >44 us surface in rocprof top-5. ----
__global__ void __launch_bounds__(256) k_pull(const int* __restrict__ rs,
        const int* __restrict__ sdat, const __half* __restrict__ h16,
        const float* __restrict__ dinv, const __half* __restrict__ zrow,
        const float* __restrict__ b0, const float* __restrict__ b1,
        const float* __restrict__ b2,
        float* __restrict__ out, int N, int E, int row0) {
    int row = row0 + blockIdx.x * 4 + (threadIdx.x >> 6);
    if (row >= 2 * N) return;
    int lane = threadIdx.x & 63;
    int q = lane >> 4;          // quarter 0..3
    int l16 = lane & 15;
    size_t NC = (size_t)N * CCH;

    const __half* hcL;
    const int* sdL;
    int beg, end;
    float ddL;
    float4 bias;
    float* op;
    float4 acc = make_float4(0.f, 0.f, 0.f, 0.f);
    if (row < N) {                          // star: q0,q1=conv0; q2,q3=conv1
        int cv = q >> 1;
        const int* rsA = rs + cv * (N + 1);
        int bg = rsA[row], eg = rsA[row + 1];
        int mid = (bg + eg) >> 1;
        beg = (q & 1) ? mid : bg;
        end = (q & 1) ? eg : mid;
        hcL = h16 + (size_t)cv * NC;
        sdL = sdat + (size_t)cv * E;
        ddL = dinv[cv * N + row];
        if (!(q & 1)) acc = gat4p(hcL + (size_t)row * CCH, l16); // self-loop
        float4 bv0 = ((const float4*)b0)[l16];
        float4 bv1 = ((const float4*)b1)[l16];
        bias = make_float4(bv0.x + bv1.x, bv0.y + bv1.y,
                           bv0.z + bv1.z, bv0.w + bv1.w);
        op = out + (size_t)row * CCH;
    } else {                                // gal: 4 segments of one list
        int r = row - N;
        const int* rs2 = rs + 2 * (N + 1);
        int bg = rs2[r], eg = rs2[r + 1];
        int len = eg - bg;
        beg = bg + ((len * q) >> 2);
        end = bg + ((len * (q + 1)) >> 2);
        hcL = h16 + 2 * NC;
        sdL = sdat + 2 * (size_t)E;
        ddL = dinv[2 * N + r];
        if (q == 0) acc = gat4p(hcL + (size_t)r * CCH, l16);
        bias = ((const float4*)b2)[l16];
        op = out + NC + (size_t)r * CCH;
    }

    int i = beg;
    for (; i + 7 < end; i += 8) {           // unpredicated steady state
        int4a q0 = *(const int4a*)(sdL + i);
        int4a q1 = *(const int4a*)(sdL + i + 4);
        float4 v0 = gat4p(hcL + (size_t)q0.x * CCH, l16);
        float4 v1 = gat4p(hcL + (size_t)q0.y * CCH, l16);
        float4 v2 = gat4p(hcL + (size_t)q0.z * CCH, l16);
        float4 v3 = gat4p(hcL + (size_t)q0.w * CCH, l16);
        float4 v4 = gat4p(hcL + (size_t)q1.x * CCH, l16);
        float4 v5 = gat4p(hcL + (size_t)q1.y * CCH, l16);
        float4 v6 = gat4p(hcL + (size_t)q1.z * CCH, l16);
        float4 v7 = gat4p(hcL + (size_t)q1.w * CCH, l16);
        acc4(acc, v0); acc4(acc, v1); acc4(acc, v2); acc4(acc, v3);
        acc4(acc, v4); acc4(acc, v5); acc4(acc, v6); acc4(acc, v7);
    }
    if (i < end) {                          // ONE masked 8-wide tail shot
        // index over-read stays inside workspace (sdat is followed by H).
        int4a q0 = *(const int4a*)(sdL + i);
        int4a q1 = *(const int4a*)(sdL + i + 4);
        const __half* p0 = hcL + (size_t)q0.x * CCH;   // i < end: valid
        const __half* p1 = (i + 1 < end) ? hcL + (size_t)q0.y * CCH : zrow;
        const __half* p2 = (i + 2 < end) ? hcL + (size_t)q0.z * CCH : zrow;
        const __half* p3 = (i + 3 < end) ? hcL + (size_t)q0.w * CCH : zrow;
        const __half* p4 = (i + 4 < end) ? hcL + (size_t)q1.x * CCH : zrow;
        const __half* p5 = (i + 5 < end) ? hcL + (size_t)q1.y * CCH : zrow;
        const __half* p6 = (i + 6 < end) ? hcL + (size_t)q1.z * CCH : zrow;
        const __half* p7 = (i + 7 < end) ? hcL + (size_t)q1.w * CCH : zrow;
        float4 v0 = gat4p(p0, l16);
        float4 v1 = gat4p(p1, l16);
        float4 v2 = gat4p(p2, l16);
        float4 v3 = gat4p(p3, l16);
        float4 v4 = gat4p(p4, l16);
        float4 v5 = gat4p(p5, l16);
        float4 v6 = gat4p(p6, l16);
        float4 v7 = gat4p(p7, l16);
        acc4(acc, v0); acc4(acc, v1); acc4(acc, v2); acc4(acc, v3);
        acc4(acc, v4); acc4(acc, v5); acc4(acc, v6); acc4(acc, v7);
    }

    float4 t;
    t.x = acc.x * ddL; t.y = acc.y * ddL; t.z = acc.z * ddL; t.w = acc.w * ddL;
    t.x += __shfl_xor(t.x, 16, 64); t.y += __shfl_xor(t.y, 16, 64);
    t.z += __shfl_xor(t.z, 16, 64); t.w += __shfl_xor(t.w, 16, 64);
    t.x += __shfl_xor(t.x, 32, 64); t.y += __shfl_xor(t.y, 32, 64);
    t.z += __shfl_xor(t.z, 32, 64); t.w += __shfl_xor(t.w, 32, 64);
    if (lane < 16) {
        t.x += bias.x; t.y += bias.y; t.z += bias.z; t.w += bias.w;
        ((float4*)op)[l16] = t;
    }
}

static inline size_t align256(size_t x) { return (x + 255) & ~(size_t)255; }

extern "C" void kernel_launch(void* const* d_in, const int* in_sizes, int n_in,
                              void* d_out, int out_size, void* d_ws, size_t ws_size,
                              hipStream_t stream) {
    const float* x_star = (const float*)d_in[0];
    const float* x_gal  = (const float*)d_in[1];
    const int*   e_ssn  = (const int*)d_in[2];
    const int*   e_ssf  = (const int*)d_in[3];
    const int*   e_ggn  = (const int*)d_in[4];
    const float* W_ssn  = (const float*)d_in[5];
    const float* W_ssf  = (const float*)d_in[6];
    const float* W_ggn  = (const float*)d_in[7];
    const float* b_ssn  = (const float*)d_in[8];
    const float* b_ssf  = (const float*)d_in[9];
    const float* b_ggn  = (const float*)d_in[10];

    const int N  = in_sizes[0] / CCH;       // 50000
    const int E  = in_sizes[2] / 2;         // 1000000
    const size_t NC = (size_t)N * CCH;
    const int NB   = (N + BKT - 1) / BKT;   // 196 buckets per conv
    const int NBLK = (E + PCH - 1) / PCH;   // 123 partition blocks per conv

    // workspace layout
    char* w = (char*)d_ws;
    __half*   h16    = (__half*)w;   w += align256((size_t)3 * NC * 2);
    float*    dinv   = (float*)w;    w += align256((size_t)3 * N * 4);
    unsigned* bdata  = (unsigned*)w; w += align256((size_t)3 * E * 4);
    int*      sdat   = (int*)w;      w += align256((size_t)3 * E * 4);
    int*      H      = (int*)w;      w += align256((size_t)3 * NBLK * NB * 4);
    int*      cnt    = (int*)w;      w += align256((size_t)3 * NB * 4);
    int*      bstart = (int*)w;      w += align256((size_t)3 * (NB + 1) * 4);
    int*      rs     = (int*)w;      w += align256((size_t)3 * (N + 1) * 4);
    __half*   zrow   = (__half*)w;   w += align256((size_t)CCH * 2);

    const int B = 256;

    hipMemsetAsync(cnt, 0, (size_t)3 * NB * 4, stream);
    k_hist<<<dim3(NBLK, 3), B, 0, stream>>>(e_ssn, e_ssf, e_ggn, H, cnt, E, NB, NBLK);
    k_bscan<<<3, 1024, 0, stream>>>(cnt, bstart, zrow, NB, E);
    k_colscan<<<dim3((NB + 3) / 4, 3), B, 0, stream>>>(H, bstart, NB, NBLK);
    k_part2<<<dim3(NBLK, 3), B, 0, stream>>>(e_ssn, e_ssf, e_ggn, H, bstart,
                                             bdata, E, NB, NBLK);
    k_sort32<<<dim3(NB, 3), B, 0, stream>>>(bdata, bstart, sdat, rs, dinv, E, N, NB);
    k_gemm_all<<<dim3((N + GR - 1) / GR, 2), B, 0, stream>>>(x_star, x_gal,
                                                             W_ssn, W_ssf, W_ggn,
                                                             dinv, h16, N);
    k_pull<<<(N + 3) / 4, B, 0, stream>>>(rs, sdat, h16, dinv, zrow,
                                          b_ssn, b_ssf, b_ggn,
                                          (float*)d_out, N, E, 0);
    k_pull<<<(N + 3) / 4, B, 0, stream>>>(rs, sdat, h16, dinv, zrow,
                                          b_ssn, b_ssf, b_ggn,
                                          (float*)d_out, N, E, N);
}